// Round 1
// baseline (572.596 us; speedup 1.0000x reference)
//
#include <hip/hip_runtime.h>
#include <math.h>

// TreeLSTM encoder, fp32 baseline.
// acts workspace layout: [node][2][128] f32 -> h at node*256, c at node*256+128.
// Needs 65536*256*4 = 64 MB of d_ws.

#define NLEAF 32768

__device__ __forceinline__ float sigf(float x) { return 1.0f / (1.0f + expf(-x)); }

// ---------------- Level 0: leaves (embed + norm-clip) ----------------
// one wave (64 lanes) per node, 4 nodes per 256-thread block
__global__ __launch_bounds__(256) void leaf_kernel(
    const int* __restrict__ tokens, const float* __restrict__ emb,
    float* __restrict__ acts, float* __restrict__ out, int n_leaves)
{
    int node = blockIdx.x * 4 + (threadIdx.x >> 6);
    if (node >= n_leaves) return;
    int lane = threadIdx.x & 63;
    int tok = tokens[node];
    float2 e = *(const float2*)(emb + (size_t)tok * 128 + lane * 2);
    float ss = e.x * e.x + e.y * e.y;
#pragma unroll
    for (int off = 32; off; off >>= 1) ss += __shfl_xor(ss, off, 64);
    float nrm = sqrtf(ss);
    float scale = fminf(1.0f, 1.0f / fmaxf(nrm, 1e-7f));
    float2 h; h.x = e.x * scale; h.y = e.y * scale;
    *(float2*)(acts + (size_t)node * 256 + lane * 2) = h;
    *(float2*)(acts + (size_t)node * 256 + 128 + lane * 2) = make_float2(0.f, 0.f);
    // output position: level 0 offset 0, count 512
    int t = node >> 9, j = node & 511;
    *(float2*)(out + ((size_t)t * 1024 + j) * 128 + lane * 2) = h;
}

// ---------------- Levels 1..9: binary combine ----------------
// 320 threads, BM=16 nodes/block. X = [lch.h | rch.h] in LDS (16x256).
// Each thread owns output columns {tid, tid+320} for all 16 rows.
// G = X @ W_bin + b_bin  (K=256, N=640), then LSTM gates.
__global__ __launch_bounds__(320) void bin_kernel(
    float* acts,
    const int* __restrict__ left, const int* __restrict__ right,
    const float* __restrict__ Wb, const float* __restrict__ bb,
    float* __restrict__ out,
    int s, int n_nodes, int out_off, int log2c)
{
    __shared__ float sh[16 * 640];  // 40 KB; first 16*256 floats = X during GEMM
    float* X = sh;
    const int tid = threadIdx.x;
    const int bm0 = blockIdx.x * 16;

    // gather children h into X (float4 granularity: 16 rows x 64 quads)
    for (int i = tid; i < 16 * 64; i += 320) {
        int m = i >> 6, kq = i & 63;
        int node = s + bm0 + m;
        int child = (kq < 32) ? left[node] : right[node];
        int q = kq & 31;
        float4 v = *(const float4*)(acts + (size_t)child * 256 + q * 4);
        *(float4*)(X + m * 256 + (kq < 32 ? 0 : 128) + q * 4) = v;
    }
    __syncthreads();

    float acc0[16], acc1[16];
#pragma unroll
    for (int m = 0; m < 16; ++m) { acc0[m] = 0.f; acc1[m] = 0.f; }

    for (int k4 = 0; k4 < 64; ++k4) {
        const int k = k4 * 4;
        float w0[4], w1[4];
#pragma unroll
        for (int r = 0; r < 4; ++r) {
            w0[r] = Wb[(k + r) * 640 + tid];
            w1[r] = Wb[(k + r) * 640 + tid + 320];
        }
#pragma unroll
        for (int m = 0; m < 16; ++m) {
            float4 xv = *(const float4*)(X + m * 256 + k);  // wave-uniform -> LDS broadcast
            acc0[m] = fmaf(xv.x, w0[0], fmaf(xv.y, w0[1], fmaf(xv.z, w0[2], fmaf(xv.w, w0[3], acc0[m]))));
            acc1[m] = fmaf(xv.x, w1[0], fmaf(xv.y, w1[1], fmaf(xv.z, w1[2], fmaf(xv.w, w1[3], acc1[m]))));
        }
    }

    float b0 = bb[tid], b1 = bb[tid + 320];
    __syncthreads();          // everyone done reading X
    float* Gm = sh;           // reuse LDS as G[16][640]
#pragma unroll
    for (int m = 0; m < 16; ++m) {
        Gm[m * 640 + tid]       = acc0[m] + b0;
        Gm[m * 640 + tid + 320] = acc1[m] + b1;
    }
    __syncthreads();

    // gates: 16 nodes x 128 dims
    for (int i = tid; i < 16 * 128; i += 320) {
        int m = i >> 7, d = i & 127;
        int node = s + bm0 + m;
        const float* g = Gm + m * 640;
        float gi = g[d], go = g[128 + d], gu = g[256 + d], gfl = g[384 + d], gfr = g[512 + d];
        float lc = acts[(size_t)left[node] * 256 + 128 + d];
        float rc = acts[(size_t)right[node] * 256 + 128 + d];
        float c = sigf(gi) * tanhf(gu) + sigf(gfl) * lc + sigf(gfr) * rc;
        float h = sigf(go) * tanhf(c);
        acts[(size_t)node * 256 + d] = h;
        acts[(size_t)node * 256 + 128 + d] = c;
        int nl = bm0 + m;
        int t = nl >> log2c, j = nl & ((1 << log2c) - 1);
        out[((size_t)t * 1024 + out_off + j) * 128 + d] = h;
    }
}

// ---------------- Level 10: unary head ----------------
// 256 threads, BM=16 nodes/block. K=128, N=512. Each thread owns cols {tid, tid+256}.
__global__ __launch_bounds__(256) void un_kernel(
    float* acts, const int* __restrict__ left,
    const float* __restrict__ Wu, const float* __restrict__ bu,
    float* __restrict__ out, int s, int n_nodes, int out_off)
{
    __shared__ float sh[16 * 512];  // 32 KB; first 16*128 = X
    float* X = sh;
    const int tid = threadIdx.x;
    const int bm0 = blockIdx.x * 16;

    for (int i = tid; i < 16 * 32; i += 256) {
        int m = i >> 5, q = i & 31;
        int node = s + bm0 + m;
        int child = left[node];
        float4 v = *(const float4*)(acts + (size_t)child * 256 + q * 4);
        *(float4*)(X + m * 128 + q * 4) = v;
    }
    __syncthreads();

    float acc0[16], acc1[16];
#pragma unroll
    for (int m = 0; m < 16; ++m) { acc0[m] = 0.f; acc1[m] = 0.f; }

    for (int k4 = 0; k4 < 32; ++k4) {
        const int k = k4 * 4;
        float w0[4], w1[4];
#pragma unroll
        for (int r = 0; r < 4; ++r) {
            w0[r] = Wu[(k + r) * 512 + tid];
            w1[r] = Wu[(k + r) * 512 + tid + 256];
        }
#pragma unroll
        for (int m = 0; m < 16; ++m) {
            float4 xv = *(const float4*)(X + m * 128 + k);
            acc0[m] = fmaf(xv.x, w0[0], fmaf(xv.y, w0[1], fmaf(xv.z, w0[2], fmaf(xv.w, w0[3], acc0[m]))));
            acc1[m] = fmaf(xv.x, w1[0], fmaf(xv.y, w1[1], fmaf(xv.z, w1[2], fmaf(xv.w, w1[3], acc1[m]))));
        }
    }

    float b0 = bu[tid], b1 = bu[tid + 256];
    __syncthreads();
    float* Gm = sh;  // [16][512]
#pragma unroll
    for (int m = 0; m < 16; ++m) {
        Gm[m * 512 + tid]       = acc0[m] + b0;
        Gm[m * 512 + tid + 256] = acc1[m] + b1;
    }
    __syncthreads();

    for (int i = tid; i < 16 * 128; i += 256) {
        int m = i >> 7, d = i & 127;
        int node = s + bm0 + m;
        const float* g = Gm + m * 512;
        float gi = g[d], go = g[128 + d], gu = g[256 + d], gf = g[384 + d];
        float cc = acts[(size_t)left[node] * 256 + 128 + d];
        float c = sigf(gi) * tanhf(gu) + sigf(gf) * cc;
        float h = sigf(go) * tanhf(c);
        acts[(size_t)node * 256 + d] = h;
        acts[(size_t)node * 256 + 128 + d] = c;
        int nl = bm0 + m;  // count=1 -> tree t=nl, j=0
        out[((size_t)nl * 1024 + out_off) * 128 + d] = h;
    }
}

extern "C" void kernel_launch(void* const* d_in, const int* in_sizes, int n_in,
                              void* d_out, int out_size, void* d_ws, size_t ws_size,
                              hipStream_t stream) {
    const int*   tokens = (const int*)d_in[0];
    const int*   left   = (const int*)d_in[1];
    const int*   right  = (const int*)d_in[2];
    const float* emb    = (const float*)d_in[3];
    const float* W_un   = (const float*)d_in[4];
    const float* b_un   = (const float*)d_in[5];
    const float* W_bin  = (const float*)d_in[6];
    const float* b_bin  = (const float*)d_in[7];
    float* out  = (float*)d_out;
    float* acts = (float*)d_ws;  // needs 64 MB

    static const int counts[11] = {512, 256, 128, 64, 32, 16, 8, 4, 2, 1, 1};
    static const int log2c[11]  = {9, 8, 7, 6, 5, 4, 3, 2, 1, 0, 0};
    int G[12]; G[0] = 0;
    for (int l = 0; l < 11; ++l) G[l + 1] = G[l] + 64 * counts[l];
    int off[11]; off[0] = 0;
    for (int l = 1; l < 11; ++l) off[l] = off[l - 1] + counts[l - 1];

    leaf_kernel<<<G[1] / 4, 256, 0, stream>>>(tokens, emb, acts, out, G[1]);

    for (int l = 1; l < 10; ++l) {
        int n = 64 * counts[l];
        bin_kernel<<<n / 16, 320, 0, stream>>>(acts, left, right, W_bin, b_bin, out,
                                               G[l], n, off[l], log2c[l]);
    }

    un_kernel<<<4, 256, 0, stream>>>(acts, left, W_un, b_un, out, G[10], 64, off[10]);
}

// Round 3
// 565.549 us; speedup vs baseline: 1.0125x; 1.0125x over previous
//
#include <hip/hip_runtime.h>
#include <math.h>

// TreeLSTM encoder, split-bf16 MFMA version.
// acts layout: [node][2][128] f32 -> h at node*256, c at node*256+128 (64 MB).
// ws layout: [0,64MB) acts ; then WhT[640][256] bf16 ; WlT[640][256] bf16.

typedef __attribute__((ext_vector_type(8))) short s8_t;
typedef __attribute__((ext_vector_type(4))) float f32x4;

__device__ __forceinline__ float sigf(float x) { return 1.0f / (1.0f + expf(-x)); }

__device__ __forceinline__ unsigned short f2bf_rne(float x) {
    unsigned int u = __builtin_bit_cast(unsigned int, x);
    unsigned int r = (u + 0x7FFFu + ((u >> 16) & 1u)) >> 16;
    return (unsigned short)r;
}
__device__ __forceinline__ float bf2f(unsigned short b) {
    return __builtin_bit_cast(float, ((unsigned int)b) << 16);
}

// ---------------- prep: W_bin [256][640] f32 -> WhT/WlT [640][256] bf16 ----------------
__global__ __launch_bounds__(256) void prep_w(
    const float* __restrict__ W, unsigned short* __restrict__ hiT,
    unsigned short* __restrict__ loT)
{
    int n = blockIdx.x;          // 640
    int k = threadIdx.x;         // 256
    float x = W[(size_t)k * 640 + n];
    unsigned short h = f2bf_rne(x);
    hiT[(size_t)n * 256 + k] = h;
    loT[(size_t)n * 256 + k] = f2bf_rne(x - bf2f(h));
}

// ---------------- Level 0: leaves ----------------
__global__ __launch_bounds__(256) void leaf_kernel(
    const int* __restrict__ tokens, const float* __restrict__ emb,
    float* __restrict__ acts, float* __restrict__ out, int n_leaves)
{
    int node = blockIdx.x * 4 + (threadIdx.x >> 6);
    if (node >= n_leaves) return;
    int lane = threadIdx.x & 63;
    int tok = tokens[node];
    float2 e = *(const float2*)(emb + (size_t)tok * 128 + lane * 2);
    float ss = e.x * e.x + e.y * e.y;
#pragma unroll
    for (int off = 32; off; off >>= 1) ss += __shfl_xor(ss, off, 64);
    float nrm = sqrtf(ss);
    float scale = fminf(1.0f, 1.0f / fmaxf(nrm, 1e-7f));
    float2 h; h.x = e.x * scale; h.y = e.y * scale;
    *(float2*)(acts + (size_t)node * 256 + lane * 2) = h;
    *(float2*)(acts + (size_t)node * 256 + 128 + lane * 2) = make_float2(0.f, 0.f);
    int t = node >> 9, j = node & 511;
    *(float2*)(out + ((size_t)t * 1024 + j) * 128 + lane * 2) = h;
}

// ---------------- Levels 1..9: binary combine, split-bf16 MFMA ----------------
// grid (ceil(M/128), 4). Block: 256 thr = 4 waves; wave w owns rows [w*32,w*32+32).
// K_ext = 768: k<256 -> Xh*Wh, 256..511 -> Xh*Wl, 512..767 -> Xl*Wh.
// BN=160 = 5 gates x 32 dims (d0..d0+31) -> gates fuse in epilogue.
__global__ __launch_bounds__(256, 2) void bin_mfma(
    float* __restrict__ acts,
    const int* __restrict__ left, const int* __restrict__ right,
    const unsigned short* __restrict__ WhT, const unsigned short* __restrict__ WlT,
    const float* __restrict__ bb, float* __restrict__ out,
    int s, int n_nodes, int out_off, int log2c)
{
    __shared__ unsigned short Ab[2][128 * 40];   // rows padded to 40 bf16 (80 B)
    __shared__ unsigned short Bb[2][160 * 40];
    __shared__ int sL[128], sR[128];

    const int tid  = threadIdx.x;
    const int lane = tid & 63;
    const int w    = tid >> 6;
    const int bm0  = blockIdx.x * 128;
    const int d0   = blockIdx.y * 32;

    // staging roles: thread t -> row t>>1, 16-elem segment t&1
    const int arow = tid >> 1, aseg = tid & 1;
    int rcl = bm0 + arow; if (rcl >= n_nodes) rcl = n_nodes - 1;
    const int cL = left[s + rcl], cR = right[s + rcl];
    if (aseg == 0) { sL[arow] = cL; sR[arow] = cR; }

    f32x4 acc[2][10];
#pragma unroll
    for (int i = 0; i < 2; ++i)
#pragma unroll
        for (int j = 0; j < 10; ++j) acc[i][j] = f32x4{0.f, 0.f, 0.f, 0.f};

    float4 areg[4];
    uint4  breg[4];

    auto load_step = [&](int st) {
        const int kk = st * 32;
        const int side = (kk >> 7) & 1;           // 0=left half, 1=right half of X
        const int off  = kk & 127;
        const float* src = acts + (size_t)(side ? cR : cL) * 256 + off + aseg * 16;
        areg[0] = *(const float4*)(src + 0);
        areg[1] = *(const float4*)(src + 4);
        areg[2] = *(const float4*)(src + 8);
        areg[3] = *(const float4*)(src + 12);
        if (tid < 160) {
            const int kor = kk & 255;
            const unsigned short* WT = ((kk >> 8) == 1) ? WlT : WhT;
            const int g = tid >> 5, dl = tid & 31;
            const unsigned short* bs = WT + (size_t)(g * 128 + d0 + dl) * 256 + kor;
            breg[0] = ((const uint4*)bs)[0];
            breg[1] = ((const uint4*)bs)[1];
            breg[2] = ((const uint4*)bs)[2];
            breg[3] = ((const uint4*)bs)[3];
        }
    };

    auto write_step = [&](int buf, int st) {
        const int isLo = ((st * 32) >> 8) == 2;
        unsigned short tmp[16];
#pragma unroll
        for (int q = 0; q < 4; ++q) {
            float xs[4] = {areg[q].x, areg[q].y, areg[q].z, areg[q].w};
#pragma unroll
            for (int e = 0; e < 4; ++e) {
                float x = xs[e];
                unsigned short u = f2bf_rne(x);
                if (isLo) u = f2bf_rne(x - bf2f(u));
                tmp[q * 4 + e] = u;
            }
        }
        s8_t v0, v1;
#pragma unroll
        for (int e = 0; e < 8; ++e) { v0[e] = (short)tmp[e]; v1[e] = (short)tmp[8 + e]; }
        unsigned short* ad = &Ab[buf][arow * 40 + aseg * 16];
        *(s8_t*)(ad)     = v0;
        *(s8_t*)(ad + 8) = v1;
        if (tid < 160) {
            unsigned short* bd = &Bb[buf][tid * 40];
            *(uint4*)(bd + 0)  = breg[0];
            *(uint4*)(bd + 8)  = breg[1];
            *(uint4*)(bd + 16) = breg[2];
            *(uint4*)(bd + 24) = breg[3];
        }
    };

    auto compute = [&](int buf) {
        const unsigned short* Ap = Ab[buf];
        const unsigned short* Bp = Bb[buf];
        s8_t af[2];
#pragma unroll
        for (int fm = 0; fm < 2; ++fm)
            af[fm] = *(const s8_t*)&Ap[(w * 32 + fm * 16 + (lane & 15)) * 40 + (lane >> 4) * 8];
#pragma unroll
        for (int fn = 0; fn < 10; ++fn) {
            s8_t bf = *(const s8_t*)&Bp[(fn * 16 + (lane & 15)) * 40 + (lane >> 4) * 8];
            acc[0][fn] = __builtin_amdgcn_mfma_f32_16x16x32_bf16(af[0], bf, acc[0][fn], 0, 0, 0);
            acc[1][fn] = __builtin_amdgcn_mfma_f32_16x16x32_bf16(af[1], bf, acc[1][fn], 0, 0, 0);
        }
    };

    load_step(0);
    write_step(0, 0);
    __syncthreads();
    for (int st = 0; st < 24; ++st) {
        if (st + 1 < 24) load_step(st + 1);     // issue-early
        compute(st & 1);
        if (st + 1 < 24) write_step((st + 1) & 1, st + 1);  // write-late
        __syncthreads();
    }

    // -------- epilogue: fused gates --------
    const int dl0 = lane & 15;
    float bias[5][2];
#pragma unroll
    for (int g = 0; g < 5; ++g) {
        bias[g][0] = bb[g * 128 + d0 + dl0];
        bias[g][1] = bb[g * 128 + d0 + 16 + dl0];
    }
#pragma unroll
    for (int fm = 0; fm < 2; ++fm) {
        const int rb = w * 32 + fm * 16 + ((lane >> 4) << 2);
#pragma unroll
        for (int reg = 0; reg < 4; ++reg) {
            const int rl = rb + reg;
            const int nl = bm0 + rl;
            const bool valid = nl < n_nodes;
            const int node = s + (valid ? nl : 0);
            const int ln = sL[rl], rn = sR[rl];
#pragma unroll
            for (int hi = 0; hi < 2; ++hi) {
                const int d = d0 + hi * 16 + dl0;
                float gi  = acc[fm][0 + hi][reg] + bias[0][hi];
                float go  = acc[fm][2 + hi][reg] + bias[1][hi];
                float gu  = acc[fm][4 + hi][reg] + bias[2][hi];
                float gfl = acc[fm][6 + hi][reg] + bias[3][hi];
                float gfr = acc[fm][8 + hi][reg] + bias[4][hi];
                float lc = acts[(size_t)ln * 256 + 128 + d];
                float rc = acts[(size_t)rn * 256 + 128 + d];
                float c = sigf(gi) * tanhf(gu) + sigf(gfl) * lc + sigf(gfr) * rc;
                float h = sigf(go) * tanhf(c);
                if (valid) {
                    acts[(size_t)node * 256 + d] = h;
                    acts[(size_t)node * 256 + 128 + d] = c;
                    const int t = nl >> log2c, j = nl & ((1 << log2c) - 1);
                    out[((size_t)t * 1024 + out_off + j) * 128 + d] = h;
                }
            }
        }
    }
}

// ---------------- Level 10: unary head (fp32, tiny) ----------------
__global__ __launch_bounds__(256) void un_kernel(
    float* acts, const int* __restrict__ left,
    const float* __restrict__ Wu, const float* __restrict__ bu,
    float* __restrict__ out, int s, int n_nodes, int out_off)
{
    __shared__ float sh[16 * 512];
    float* X = sh;
    const int tid = threadIdx.x;
    const int bm0 = blockIdx.x * 16;

    for (int i = tid; i < 16 * 32; i += 256) {
        int m = i >> 5, q = i & 31;
        int node = s + bm0 + m;
        int child = left[node];
        float4 v = *(const float4*)(acts + (size_t)child * 256 + q * 4);
        *(float4*)(X + m * 128 + q * 4) = v;
    }
    __syncthreads();

    float acc0[16], acc1[16];
#pragma unroll
    for (int m = 0; m < 16; ++m) { acc0[m] = 0.f; acc1[m] = 0.f; }

    for (int k4 = 0; k4 < 32; ++k4) {
        const int k = k4 * 4;
        float w0[4], w1[4];
#pragma unroll
        for (int r = 0; r < 4; ++r) {
            w0[r] = Wu[(k + r) * 512 + tid];
            w1[r] = Wu[(k + r) * 512 + tid + 256];
        }
#pragma unroll
        for (int m = 0; m < 16; ++m) {
            float4 xv = *(const float4*)(X + m * 128 + k);
            acc0[m] = fmaf(xv.x, w0[0], fmaf(xv.y, w0[1], fmaf(xv.z, w0[2], fmaf(xv.w, w0[3], acc0[m]))));
            acc1[m] = fmaf(xv.x, w1[0], fmaf(xv.y, w1[1], fmaf(xv.z, w1[2], fmaf(xv.w, w1[3], acc1[m]))));
        }
    }

    float b0 = bu[tid], b1 = bu[tid + 256];
    __syncthreads();
    float* Gm = sh;
#pragma unroll
    for (int m = 0; m < 16; ++m) {
        Gm[m * 512 + tid]       = acc0[m] + b0;
        Gm[m * 512 + tid + 256] = acc1[m] + b1;
    }
    __syncthreads();

    for (int i = tid; i < 16 * 128; i += 256) {
        int m = i >> 7, d = i & 127;
        int node = s + bm0 + m;
        const float* g = Gm + m * 512;
        float gi = g[d], go = g[128 + d], gu = g[256 + d], gf = g[384 + d];
        float cc = acts[(size_t)left[node] * 256 + 128 + d];
        float c = sigf(gi) * tanhf(gu) + sigf(gf) * cc;
        float h = sigf(go) * tanhf(c);
        acts[(size_t)node * 256 + d] = h;
        acts[(size_t)node * 256 + 128 + d] = c;
        int nl = bm0 + m;
        out[((size_t)nl * 1024 + out_off) * 128 + d] = h;
    }
}

extern "C" void kernel_launch(void* const* d_in, const int* in_sizes, int n_in,
                              void* d_out, int out_size, void* d_ws, size_t ws_size,
                              hipStream_t stream) {
    const int*   tokens = (const int*)d_in[0];
    const int*   left   = (const int*)d_in[1];
    const int*   right  = (const int*)d_in[2];
    const float* emb    = (const float*)d_in[3];
    const float* W_un   = (const float*)d_in[4];
    const float* b_un   = (const float*)d_in[5];
    const float* W_bin  = (const float*)d_in[6];
    const float* b_bin  = (const float*)d_in[7];
    float* out  = (float*)d_out;
    float* acts = (float*)d_ws;                       // 64 MB
    unsigned short* WhT = (unsigned short*)((char*)d_ws + 67108864);
    unsigned short* WlT = WhT + 640 * 256;            // +320 KB each

    static const int counts[11] = {512, 256, 128, 64, 32, 16, 8, 4, 2, 1, 1};
    static const int log2c[11]  = {9, 8, 7, 6, 5, 4, 3, 2, 1, 0, 0};
    int G[12]; G[0] = 0;
    for (int l = 0; l < 11; ++l) G[l + 1] = G[l] + 64 * counts[l];
    int off[11]; off[0] = 0;
    for (int l = 1; l < 11; ++l) off[l] = off[l - 1] + counts[l - 1];

    prep_w<<<640, 256, 0, stream>>>(W_bin, WhT, WlT);
    leaf_kernel<<<G[1] / 4, 256, 0, stream>>>(tokens, emb, acts, out, G[1]);

    for (int l = 1; l < 10; ++l) {
        int n = 64 * counts[l];
        int gm = (n + 127) / 128;
        bin_mfma<<<dim3(gm, 4), 256, 0, stream>>>(acts, left, right, WhT, WlT,
                                                  b_bin, out, G[l], n, off[l], log2c[l]);
    }

    un_kernel<<<4, 256, 0, stream>>>(acts, left, W_un, b_un, out, G[10], 64, off[10]);
}

// Round 4
// 449.014 us; speedup vs baseline: 1.2752x; 1.2595x over previous
//
#include <hip/hip_runtime.h>
#include <math.h>

// TreeLSTM encoder, split-bf16 MFMA v2: global_load_lds staging, SoA acts planes.
// ws layout (bytes):
//   [0,16M)    Hhi plane: [65536 nodes][128] bf16   (h high half)
//   [16M,32M)  Hlo plane: [65536][128] bf16         (h low half)
//   [32M,64M)  C plane:   [65536][128] f32
//   [64M,+640K) W_ext:    [640 cols][512] bf16  (k<256 = hi(W_bin), k>=256 = lo)
// K_ext = 768: term0 Xh*Wh, term1 Xh*Wl, term2 Xl*Wh.

typedef __attribute__((ext_vector_type(8))) short s8_t;
typedef __attribute__((ext_vector_type(4))) float f32x4;

#define PLANE_DELTA 8388608   // elems (ushort) between Hhi and Hlo planes

__device__ __forceinline__ float sigf(float x){ return 1.0f/(1.0f+expf(-x)); }

__device__ __forceinline__ unsigned short f2bf_rne(float x){
    unsigned int u = __builtin_bit_cast(unsigned int, x);
    unsigned int r = (u + 0x7FFFu + ((u>>16)&1u)) >> 16;
    return (unsigned short)r;
}
__device__ __forceinline__ float bf2f(unsigned short b){
    return __builtin_bit_cast(float, ((unsigned int)b)<<16);
}
__device__ __forceinline__ void gl_lds16(const void* g, void* l){
    __builtin_amdgcn_global_load_lds(
        (const __attribute__((address_space(1))) unsigned int*)g,
        (__attribute__((address_space(3))) unsigned int*)l, 16, 0, 0);
}

// ---------------- prep: W_bin [256][640] f32 -> W_ext [640][512] bf16 (hi|lo) ----------------
__global__ __launch_bounds__(256) void prep_w(
    const float* __restrict__ W, unsigned short* __restrict__ Wext)
{
    int n = blockIdx.x;          // 640 cols
    int k = threadIdx.x;         // 256 k
    float x = W[(size_t)k * 640 + n];
    unsigned short h = f2bf_rne(x);
    Wext[(size_t)n * 512 + k]       = h;
    Wext[(size_t)n * 512 + 256 + k] = f2bf_rne(x - bf2f(h));
}

// ---------------- Level 0: leaves ----------------
__global__ __launch_bounds__(256) void leaf_kernel(
    const int* __restrict__ tokens, const float* __restrict__ emb,
    unsigned short* __restrict__ Hhi, float* __restrict__ C,
    float* __restrict__ out, int n_leaves)
{
    int node = blockIdx.x * 4 + (threadIdx.x >> 6);
    if (node >= n_leaves) return;
    int lane = threadIdx.x & 63;
    int tok = tokens[node];
    float2 e = *(const float2*)(emb + (size_t)tok * 128 + lane * 2);
    float ss = e.x * e.x + e.y * e.y;
#pragma unroll
    for (int off = 32; off; off >>= 1) ss += __shfl_xor(ss, off, 64);
    float nrm = sqrtf(ss);
    float scale = fminf(1.0f, 1.0f / fmaxf(nrm, 1e-7f));
    float hx = e.x * scale, hy = e.y * scale;
    unsigned short hxh = f2bf_rne(hx), hyh = f2bf_rne(hy);
    unsigned short hxl = f2bf_rne(hx - bf2f(hxh)), hyl = f2bf_rne(hy - bf2f(hyh));
    size_t p = (size_t)node * 128 + lane * 2;
    *(unsigned int*)(Hhi + p)               = (unsigned int)hxh | ((unsigned int)hyh << 16);
    *(unsigned int*)(Hhi + p + PLANE_DELTA) = (unsigned int)hxl | ((unsigned int)hyl << 16);
    *(float2*)(C + p) = make_float2(0.f, 0.f);
    int t = node >> 9, j = node & 511;
    *(float2*)(out + ((size_t)t * 1024 + j) * 128 + lane * 2) = make_float2(hx, hy);
}

// ---------------- Levels 1..9: binary combine, MFMA + global_load_lds ----------------
// grid (ceil(M/128), 4). 256 thr = 4 waves; wave w rows [w*32, w*32+32).
// BN=160 = 5 gates x 32 dims (d0..d0+31). 24 K-steps of 32 ext-k.
// LDS: A-tile 128 rows x 64B, B-tile 160 rows x 64B, double-buffered.
// Chunk swizzle: slot = chunk ^ ((row>>1)&3)  (conflict-free-ish ds_read_b128).
__global__ __launch_bounds__(256, 4) void bin2(
    unsigned short* __restrict__ Hhi,     // Hlo = Hhi + PLANE_DELTA
    float* __restrict__ C,
    const int* __restrict__ left, const int* __restrict__ right,
    const unsigned short* __restrict__ Wext, const float* __restrict__ bb,
    float* __restrict__ out,
    int s, int n_nodes, int out_off, int log2c)
{
    __shared__ unsigned short Ab[2][512 * 8];   // 8KB each
    __shared__ unsigned short Bb[2][640 * 8];   // 10KB each
    __shared__ int sLR[256];                    // [0,128) left, [128,256) right

    const int tid  = threadIdx.x;
    const int lane = tid & 63;
    const int w    = tid >> 6;
    const int bm0  = blockIdx.x * 128;
    const int d0   = blockIdx.y * 32;

    if (tid < 128) {
        int r = bm0 + tid; if (r >= n_nodes) r = n_nodes - 1;
        sLR[tid]       = left[s + r];
        sLR[128 + tid] = right[s + r];
    }
    __syncthreads();

    // per-thread staging constants
    int aOffL[2], aOffR[2];        // byte offset into Hhi plane: child*256 + g*16
#pragma unroll
    for (int j = 0; j < 2; ++j) {
        int ch = tid + j * 256;    // A chunk id (512 total)
        int row = ch >> 2, slot = ch & 3;
        int g = slot ^ ((row >> 1) & 3);
        aOffL[j] = sLR[row] * 256 + g * 16;
        aOffR[j] = sLR[128 + row] * 256 + g * 16;
    }
    int bOff[3];                   // byte offset into Wext: wcol*1024 + g*16
#pragma unroll
    for (int j = 0; j < 3; ++j) {
        int ch = tid + j * 256;    // B chunk id (640 valid)
        int n = ch >> 2, slot = ch & 3;
        int g = slot ^ ((n >> 1) & 3);
        int wcol = (n >> 5) * 128 + d0 + (n & 31);
        bOff[j] = wcol * 1024 + g * 16;
    }

    const char* HhiB  = (const char*)Hhi;
    const char* WextB = (const char*)Wext;

    f32x4 acc[2][10];
#pragma unroll
    for (int i = 0; i < 2; ++i)
#pragma unroll
        for (int j = 0; j < 10; ++j) acc[i][j] = f32x4{0.f, 0.f, 0.f, 0.f};

    auto stage = [&](int st, int buf) {
        const int t = st >> 3;                  // term 0,1,2
        const int k256 = (st & 7) * 32;         // 0..224
        const int side = k256 >> 7;             // 0 = left child, 1 = right
        const int aoffB = ((t == 2) ? PLANE_DELTA * 2 : 0) + (k256 & 127) * 2;
        const int koffB = ((t == 1) ? (256 + k256) : k256) * 2;
#pragma unroll
        for (int j = 0; j < 2; ++j) {
            const char* ga = HhiB + (size_t)((side ? aOffR[j] : aOffL[j]) + aoffB);
            gl_lds16(ga, &Ab[buf][(w * 64 + j * 256) * 8]);
        }
#pragma unroll
        for (int j = 0; j < 2; ++j) {
            const char* gb = WextB + (size_t)(bOff[j] + koffB);
            gl_lds16(gb, &Bb[buf][(w * 64 + j * 256) * 8]);
        }
        if (w < 2) {
            const char* gb = WextB + (size_t)(bOff[2] + koffB);
            gl_lds16(gb, &Bb[buf][(512 + w * 64) * 8]);
        }
    };

    const int r15 = lane & 15;
    const int sl  = (lane >> 4) ^ ((r15 >> 1) & 3);
    const int offA = w * 2048 + r15 * 64 + sl * 16;   // bytes
    const int offB = r15 * 64 + sl * 16;

    auto compute = [&](int buf) {
        const char* Ap = (const char*)Ab[buf];
        const char* Bp = (const char*)Bb[buf];
        s8_t a0 = *(const s8_t*)(Ap + offA);
        s8_t a1 = *(const s8_t*)(Ap + offA + 1024);
#pragma unroll
        for (int fn = 0; fn < 10; ++fn) {
            s8_t bf = *(const s8_t*)(Bp + offB + fn * 1024);
            acc[0][fn] = __builtin_amdgcn_mfma_f32_16x16x32_bf16(a0, bf, acc[0][fn], 0, 0, 0);
            acc[1][fn] = __builtin_amdgcn_mfma_f32_16x16x32_bf16(a1, bf, acc[1][fn], 0, 0, 0);
        }
    };

    stage(0, 0);
    __syncthreads();
    for (int st = 0; st < 24; ++st) {
        if (st < 23) stage(st + 1, (st + 1) & 1);
        compute(st & 1);
        __syncthreads();
    }

    // -------- epilogue: fused LSTM gates --------
    const int dl0 = r15;
    float bias[5][2];
#pragma unroll
    for (int g = 0; g < 5; ++g) {
        bias[g][0] = bb[g * 128 + d0 + dl0];
        bias[g][1] = bb[g * 128 + d0 + 16 + dl0];
    }
#pragma unroll
    for (int fm = 0; fm < 2; ++fm) {
        const int rb = w * 32 + fm * 16 + ((lane >> 4) << 2);
#pragma unroll
        for (int reg = 0; reg < 4; ++reg) {
            const int rl = rb + reg;
            const int nl = bm0 + rl;
            const bool valid = nl < n_nodes;
            const int node = s + (valid ? nl : 0);
            const int ln = sLR[rl], rn = sLR[128 + rl];
#pragma unroll
            for (int hi = 0; hi < 2; ++hi) {
                const int d = d0 + hi * 16 + dl0;
                float gi  = acc[fm][0 + hi][reg] + bias[0][hi];
                float go  = acc[fm][2 + hi][reg] + bias[1][hi];
                float gu  = acc[fm][4 + hi][reg] + bias[2][hi];
                float gfl = acc[fm][6 + hi][reg] + bias[3][hi];
                float gfr = acc[fm][8 + hi][reg] + bias[4][hi];
                float lc = C[(size_t)ln * 128 + d];
                float rc = C[(size_t)rn * 128 + d];
                float c = sigf(gi) * tanhf(gu) + sigf(gfl) * lc + sigf(gfr) * rc;
                float h = sigf(go) * tanhf(c);
                if (valid) {
                    size_t p = (size_t)node * 128 + d;
                    unsigned short hh = f2bf_rne(h);
                    Hhi[p]               = hh;
                    Hhi[p + PLANE_DELTA] = f2bf_rne(h - bf2f(hh));
                    C[p] = c;
                    const int tt = nl >> log2c, j = nl & ((1 << log2c) - 1);
                    out[((size_t)tt * 1024 + out_off + j) * 128 + d] = h;
                }
            }
        }
    }
}

// ---------------- Level 10: unary head (fp32, tiny) ----------------
__global__ __launch_bounds__(256) void un_kernel(
    const unsigned short* __restrict__ Hhi, const float* __restrict__ C,
    const int* __restrict__ left,
    const float* __restrict__ Wu, const float* __restrict__ bu,
    float* __restrict__ out, int s, int out_off)
{
    __shared__ float sh[16 * 512];
    float* X = sh;
    const int tid = threadIdx.x;
    const int bm0 = blockIdx.x * 16;

    for (int i = tid; i < 16 * 128; i += 256) {
        int m = i >> 7, d = i & 127;
        int ch = left[s + bm0 + m];
        size_t p = (size_t)ch * 128 + d;
        X[m * 128 + d] = bf2f(Hhi[p]) + bf2f(Hhi[p + PLANE_DELTA]);
    }
    __syncthreads();

    float acc0[16], acc1[16];
#pragma unroll
    for (int m = 0; m < 16; ++m) { acc0[m] = 0.f; acc1[m] = 0.f; }

    for (int k4 = 0; k4 < 32; ++k4) {
        const int k = k4 * 4;
        float w0[4], w1[4];
#pragma unroll
        for (int r = 0; r < 4; ++r) {
            w0[r] = Wu[(k + r) * 512 + tid];
            w1[r] = Wu[(k + r) * 512 + tid + 256];
        }
#pragma unroll
        for (int m = 0; m < 16; ++m) {
            float4 xv = *(const float4*)(X + m * 128 + k);
            acc0[m] = fmaf(xv.x, w0[0], fmaf(xv.y, w0[1], fmaf(xv.z, w0[2], fmaf(xv.w, w0[3], acc0[m]))));
            acc1[m] = fmaf(xv.x, w1[0], fmaf(xv.y, w1[1], fmaf(xv.z, w1[2], fmaf(xv.w, w1[3], acc1[m]))));
        }
    }

    float b0 = bu[tid], b1 = bu[tid + 256];
    __syncthreads();
    float* Gm = sh;
#pragma unroll
    for (int m = 0; m < 16; ++m) {
        Gm[m * 512 + tid]       = acc0[m] + b0;
        Gm[m * 512 + tid + 256] = acc1[m] + b1;
    }
    __syncthreads();

    for (int i = tid; i < 16 * 128; i += 256) {
        int m = i >> 7, d = i & 127;
        const float* g = Gm + m * 512;
        float gi = g[d], go = g[128 + d], gu = g[256 + d], gf = g[384 + d];
        float cc = C[(size_t)left[s + bm0 + m] * 128 + d];
        float c = sigf(gi) * tanhf(gu) + sigf(gf) * cc;
        float h = sigf(go) * tanhf(c);
        out[((size_t)(bm0 + m) * 1024 + out_off) * 128 + d] = h;
    }
}

extern "C" void kernel_launch(void* const* d_in, const int* in_sizes, int n_in,
                              void* d_out, int out_size, void* d_ws, size_t ws_size,
                              hipStream_t stream) {
    const int*   tokens = (const int*)d_in[0];
    const int*   left   = (const int*)d_in[1];
    const int*   right  = (const int*)d_in[2];
    const float* emb    = (const float*)d_in[3];
    const float* W_un   = (const float*)d_in[4];
    const float* b_un   = (const float*)d_in[5];
    const float* W_bin  = (const float*)d_in[6];
    const float* b_bin  = (const float*)d_in[7];
    float* out = (float*)d_out;

    unsigned short* Hhi  = (unsigned short*)d_ws;                       // 16M hi + 16M lo
    float*          C    = (float*)((char*)d_ws + 33554432);            // 32M
    unsigned short* Wext = (unsigned short*)((char*)d_ws + 67108864);   // 640K

    static const int counts[11] = {512, 256, 128, 64, 32, 16, 8, 4, 2, 1, 1};
    static const int log2c[11]  = {9, 8, 7, 6, 5, 4, 3, 2, 1, 0, 0};
    int G[12]; G[0] = 0;
    for (int l = 0; l < 11; ++l) G[l + 1] = G[l] + 64 * counts[l];
    int off[11]; off[0] = 0;
    for (int l = 1; l < 11; ++l) off[l] = off[l - 1] + counts[l - 1];

    prep_w<<<640, 256, 0, stream>>>(W_bin, Wext);
    leaf_kernel<<<G[1] / 4, 256, 0, stream>>>(tokens, emb, Hhi, C, out, G[1]);

    for (int l = 1; l < 10; ++l) {
        int n = 64 * counts[l];
        int gm = (n + 127) / 128;
        bin2<<<dim3(gm, 4), 256, 0, stream>>>(Hhi, C, left, right, Wext, b_bin,
                                              out, G[l], n, off[l], log2c[l]);
    }

    un_kernel<<<4, 256, 0, stream>>>(Hhi, C, left, W_un, b_un, out, G[10], off[10]);
}

// Round 7
// 350.758 us; speedup vs baseline: 1.6325x; 1.2801x over previous
//
#include <hip/hip_runtime.h>
#include <math.h>

// TreeLSTM encoder v3: per-level launches (known-good), counted-vmcnt pipelined K-loop.
// ws layout (bytes):
//   [0,16M)    Hhi plane: [65536][128] bf16
//   [16M,32M)  Hlo plane: [65536][128] bf16
//   [32M,64M)  C plane:   [65536][128] f32
//   [64M,+640K) W_ext:    [640 cols][512] bf16 (k<256 hi, k>=256 lo)
// K_ext = 768: term0 Xh*Wh, term1 Xh*Wl, term2 Xl*Wh.

typedef __attribute__((ext_vector_type(8))) short s8_t;
typedef __attribute__((ext_vector_type(4))) float f32x4;

#define PLANE_DELTA 8388608   // ushorts between Hhi and Hlo planes

__device__ __forceinline__ float sigf(float x){ return 1.0f/(1.0f+expf(-x)); }

__device__ __forceinline__ unsigned short f2bf_rne(float x){
    unsigned int u = __builtin_bit_cast(unsigned int, x);
    unsigned int r = (u + 0x7FFFu + ((u>>16)&1u)) >> 16;
    return (unsigned short)r;
}
__device__ __forceinline__ float bf2f(unsigned short b){
    return __builtin_bit_cast(float, ((unsigned int)b)<<16);
}
__device__ __forceinline__ void gl_lds16(const void* g, void* l){
    __builtin_amdgcn_global_load_lds(
        (const __attribute__((address_space(1))) unsigned int*)g,
        (__attribute__((address_space(3))) unsigned int*)l, 16, 0, 0);
}

// ---------------- prep: W_bin [256][640] f32 -> W_ext [640][512] bf16 (hi|lo) ----------------
__global__ __launch_bounds__(256) void prep_w(
    const float* __restrict__ W, unsigned short* __restrict__ Wext)
{
    int n = blockIdx.x;
    int k = threadIdx.x;
    float x = W[(size_t)k * 640 + n];
    unsigned short h = f2bf_rne(x);
    Wext[(size_t)n * 512 + k]       = h;
    Wext[(size_t)n * 512 + 256 + k] = f2bf_rne(x - bf2f(h));
}

// ---------------- Level 0: leaves ----------------
__global__ __launch_bounds__(256) void leaf_kernel(
    const int* __restrict__ tokens, const float* __restrict__ emb,
    unsigned short* __restrict__ Hhi, float* __restrict__ C,
    float* __restrict__ out, int n_leaves)
{
    int node = blockIdx.x * 4 + (threadIdx.x >> 6);
    if (node >= n_leaves) return;
    int lane = threadIdx.x & 63;
    int tok = tokens[node];
    float2 e = *(const float2*)(emb + (size_t)tok * 128 + lane * 2);
    float ss = e.x * e.x + e.y * e.y;
#pragma unroll
    for (int off = 32; off; off >>= 1) ss += __shfl_xor(ss, off, 64);
    float nrm = sqrtf(ss);
    float scale = fminf(1.0f, 1.0f / fmaxf(nrm, 1e-7f));
    float hx = e.x * scale, hy = e.y * scale;
    unsigned short hxh = f2bf_rne(hx), hyh = f2bf_rne(hy);
    unsigned short hxl = f2bf_rne(hx - bf2f(hxh)), hyl = f2bf_rne(hy - bf2f(hyh));
    size_t p = (size_t)node * 128 + lane * 2;
    *(unsigned int*)(Hhi + p)               = (unsigned int)hxh | ((unsigned int)hyh << 16);
    *(unsigned int*)(Hhi + p + PLANE_DELTA) = (unsigned int)hxl | ((unsigned int)hyl << 16);
    *(float2*)(C + p) = make_float2(0.f, 0.f);
    int t = node >> 9, j = node & 511;
    *(float2*)(out + ((size_t)t * 1024 + j) * 128 + lane * 2) = make_float2(hx, hy);
}

// ---------------- Levels 1..9: binary combine, MFMA + depth-3 counted-vmcnt pipeline ----
// grid (ceil(M/128), 4). 256 thr = 4 waves; wave w rows [w*32, w*32+32).
// BN=160 = 5 gates x 32 dims. 24 K-steps of 32 ext-k. 4 LDS buffers, prefetch depth 3.
// Every thread issues exactly 5 global_load_lds per stage (waves 2-3's 5th goes to a
// dummy LDS strip) so s_waitcnt vmcnt(N) counts are wave-uniform.
__global__ __launch_bounds__(256, 2) void bin3(
    unsigned short* __restrict__ Hhi,     // Hlo = Hhi + PLANE_DELTA
    float* __restrict__ C,
    const int* __restrict__ left, const int* __restrict__ right,
    const unsigned short* __restrict__ Wext, const float* __restrict__ bb,
    float* __restrict__ out,
    int s, int n_nodes, int out_off, int log2c)
{
    __shared__ __align__(16) unsigned short SL[4 * 9216];   // 4 bufs x (8KB A + 10KB B)
    __shared__ __align__(16) unsigned short dmy[1024];      // 2KB dummy strip
    __shared__ int sLR[256];

    const int tid  = threadIdx.x;
    const int lane = tid & 63;
    const int w    = tid >> 6;
    const int bm0  = blockIdx.x * 128;
    const int d0   = blockIdx.y * 32;

    if (tid < 128) {
        int r = bm0 + tid; if (r >= n_nodes) r = n_nodes - 1;
        sLR[tid]       = left[s + r];
        sLR[128 + tid] = right[s + r];
    }
    __syncthreads();

    // per-thread staging source offsets (chunk swizzle: g = slot ^ ((row>>1)&3))
    int aOffL[2], aOffR[2];
#pragma unroll
    for (int j = 0; j < 2; ++j) {
        int ch = tid + j * 256, row = ch >> 2, slot = ch & 3;
        int g = slot ^ ((row >> 1) & 3);
        aOffL[j] = sLR[row] * 256 + g * 16;
        aOffR[j] = sLR[128 + row] * 256 + g * 16;
    }
    int bOff0, bOff1, bOff2;
    {
        int nn = tid >> 2, slot = tid & 3;
        int g = slot ^ ((nn >> 1) & 3);
        bOff0 = ((nn >> 5) * 128 + d0 + (nn & 31)) * 1024 + g * 16;
    }
    {
        int ch = tid + 256, nn = ch >> 2, slot = ch & 3;
        int g = slot ^ ((nn >> 1) & 3);
        bOff1 = ((nn >> 5) * 128 + d0 + (nn & 31)) * 1024 + g * 16;
    }
    if (tid < 128) {
        int ch = tid + 512, nn = ch >> 2, slot = ch & 3;
        int g = slot ^ ((nn >> 1) & 3);
        bOff2 = ((nn >> 5) * 128 + d0 + (nn & 31)) * 1024 + g * 16;
    } else {
        bOff2 = 0;   // dummy load, always-valid source
    }

    const char* HhiB  = (const char*)Hhi;
    const char* WextB = (const char*)Wext;

    f32x4 acc[2][10];
#pragma unroll
    for (int i = 0; i < 2; ++i)
#pragma unroll
        for (int j = 0; j < 10; ++j) acc[i][j] = f32x4{0.f, 0.f, 0.f, 0.f};

    auto stage = [&](int st, int buf) {
        const int tm    = st >> 3;                 // term 0,1,2
        const int k256  = (st & 7) * 32;
        const int side  = k256 >> 7;               // 0 = left child, 1 = right
        const int aoffB = ((tm == 2) ? PLANE_DELTA * 2 : 0) + (k256 & 127) * 2;
        const int koffB = ((tm == 1) ? (256 + k256) : k256) * 2;
        char* Abase = (char*)SL + buf * 18432;
        char* Bbase = Abase + 8192;
        const int a0 = side ? aOffR[0] : aOffL[0];
        const int a1 = side ? aOffR[1] : aOffL[1];
        gl_lds16(HhiB + (size_t)(a0 + aoffB), Abase + w * 1024);
        gl_lds16(HhiB + (size_t)(a1 + aoffB), Abase + 4096 + w * 1024);
        gl_lds16(WextB + (size_t)(bOff0 + koffB), Bbase + w * 1024);
        gl_lds16(WextB + (size_t)(bOff1 + koffB), Bbase + 4096 + w * 1024);
        gl_lds16(WextB + (size_t)(bOff2 + koffB),
                 (w < 2) ? (void*)(Bbase + 8192 + w * 1024)
                         : (void*)((char*)dmy + (w - 2) * 1024));
    };

    const int r15  = lane & 15;
    const int sl_  = (lane >> 4) ^ ((r15 >> 1) & 3);
    const int offA = w * 2048 + r15 * 64 + sl_ * 16;
    const int offB = r15 * 64 + sl_ * 16;

    stage(0, 0);
    stage(1, 1);
    stage(2, 2);
    int cbuf = 0, sbuf = 3;
#pragma unroll 1
    for (int st = 0; st < 24; ++st) {
        if (st <= 21)      asm volatile("s_waitcnt vmcnt(10)" ::: "memory");
        else if (st == 22) asm volatile("s_waitcnt vmcnt(5)"  ::: "memory");
        else               asm volatile("s_waitcnt vmcnt(0)"  ::: "memory");
        __builtin_amdgcn_sched_barrier(0);
        __builtin_amdgcn_s_barrier();
        __builtin_amdgcn_sched_barrier(0);
        if (st + 3 < 24) stage(st + 3, sbuf);
        const char* Ap = (const char*)SL + cbuf * 18432;
        const char* Bp = Ap + 8192;
        s8_t a0v = *(const s8_t*)(Ap + offA);
        s8_t a1v = *(const s8_t*)(Ap + offA + 1024);
#pragma unroll
        for (int fn = 0; fn < 10; ++fn) {
            s8_t bf = *(const s8_t*)(Bp + offB + fn * 1024);
            acc[0][fn] = __builtin_amdgcn_mfma_f32_16x16x32_bf16(a0v, bf, acc[0][fn], 0, 0, 0);
            acc[1][fn] = __builtin_amdgcn_mfma_f32_16x16x32_bf16(a1v, bf, acc[1][fn], 0, 0, 0);
        }
        cbuf = (cbuf == 3) ? 0 : cbuf + 1;
        sbuf = (sbuf == 3) ? 0 : sbuf + 1;
    }

    // -------- epilogue: fused LSTM gates --------
    float bias[5][2];
#pragma unroll
    for (int g = 0; g < 5; ++g) {
        bias[g][0] = bb[g * 128 + d0 + r15];
        bias[g][1] = bb[g * 128 + d0 + 16 + r15];
    }
#pragma unroll
    for (int fm = 0; fm < 2; ++fm) {
        const int rb = w * 32 + fm * 16 + ((lane >> 4) << 2);
#pragma unroll
        for (int reg = 0; reg < 4; ++reg) {
            const int rl = rb + reg;
            const int nl = bm0 + rl;
            const bool valid = nl < n_nodes;
            const int node = s + (valid ? nl : 0);
            const int ln = sLR[rl], rn = sLR[128 + rl];
#pragma unroll
            for (int hi = 0; hi < 2; ++hi) {
                const int d = d0 + hi * 16 + r15;
                float gi  = acc[fm][0 + hi][reg] + bias[0][hi];
                float go  = acc[fm][2 + hi][reg] + bias[1][hi];
                float gu  = acc[fm][4 + hi][reg] + bias[2][hi];
                float gfl = acc[fm][6 + hi][reg] + bias[3][hi];
                float gfr = acc[fm][8 + hi][reg] + bias[4][hi];
                float lc = C[(size_t)ln * 128 + d];
                float rc = C[(size_t)rn * 128 + d];
                float c = sigf(gi) * tanhf(gu) + sigf(gfl) * lc + sigf(gfr) * rc;
                float h = sigf(go) * tanhf(c);
                if (valid) {
                    size_t p = (size_t)node * 128 + d;
                    unsigned short hh = f2bf_rne(h);
                    Hhi[p]               = hh;
                    Hhi[p + PLANE_DELTA] = f2bf_rne(h - bf2f(hh));
                    C[p] = c;
                    const int tt = nl >> log2c, j = nl & ((1 << log2c) - 1);
                    out[((size_t)tt * 1024 + out_off + j) * 128 + d] = h;
                }
            }
        }
    }
}

// ---------------- Level 10: unary head (fp32, tiny) ----------------
__global__ __launch_bounds__(256) void un_kernel(
    const unsigned short* __restrict__ Hhi, const float* __restrict__ C,
    const int* __restrict__ left,
    const float* __restrict__ Wu, const float* __restrict__ bu,
    float* __restrict__ out, int s, int out_off)
{
    __shared__ float sh[16 * 512];
    float* X = sh;
    const int tid = threadIdx.x;
    const int bm0 = blockIdx.x * 16;

    for (int i = tid; i < 16 * 128; i += 256) {
        int m = i >> 7, d = i & 127;
        int ch = left[s + bm0 + m];
        size_t p = (size_t)ch * 128 + d;
        X[m * 128 + d] = bf2f(Hhi[p]) + bf2f(Hhi[p + PLANE_DELTA]);
    }
    __syncthreads();

    float acc0[16], acc1[16];
#pragma unroll
    for (int m = 0; m < 16; ++m) { acc0[m] = 0.f; acc1[m] = 0.f; }

    for (int k4 = 0; k4 < 32; ++k4) {
        const int k = k4 * 4;
        float w0[4], w1[4];
#pragma unroll
        for (int r = 0; r < 4; ++r) {
            w0[r] = Wu[(k + r) * 512 + tid];
            w1[r] = Wu[(k + r) * 512 + tid + 256];
        }
#pragma unroll
        for (int m = 0; m < 16; ++m) {
            float4 xv = *(const float4*)(X + m * 128 + k);
            acc0[m] = fmaf(xv.x, w0[0], fmaf(xv.y, w0[1], fmaf(xv.z, w0[2], fmaf(xv.w, w0[3], acc0[m]))));
            acc1[m] = fmaf(xv.x, w1[0], fmaf(xv.y, w1[1], fmaf(xv.z, w1[2], fmaf(xv.w, w1[3], acc1[m]))));
        }
    }

    float b0 = bu[tid], b1 = bu[tid + 256];
    __syncthreads();
    float* Gm = sh;
#pragma unroll
    for (int m = 0; m < 16; ++m) {
        Gm[m * 512 + tid]       = acc0[m] + b0;
        Gm[m * 512 + tid + 256] = acc1[m] + b1;
    }
    __syncthreads();

    for (int i = tid; i < 16 * 128; i += 256) {
        int m = i >> 7, d = i & 127;
        const float* g = Gm + m * 512;
        float gi = g[d], go = g[128 + d], gu = g[256 + d], gf = g[384 + d];
        float cc = C[(size_t)left[s + bm0 + m] * 128 + d];
        float c = sigf(gi) * tanhf(gu) + sigf(gf) * cc;
        float h = sigf(go) * tanhf(c);
        out[((size_t)(bm0 + m) * 1024 + out_off) * 128 + d] = h;
    }
}

extern "C" void kernel_launch(void* const* d_in, const int* in_sizes, int n_in,
                              void* d_out, int out_size, void* d_ws, size_t ws_size,
                              hipStream_t stream) {
    const int*   tokens = (const int*)d_in[0];
    const int*   left   = (const int*)d_in[1];
    const int*   right  = (const int*)d_in[2];
    const float* emb    = (const float*)d_in[3];
    const float* W_un   = (const float*)d_in[4];
    const float* b_un   = (const float*)d_in[5];
    const float* W_bin  = (const float*)d_in[6];
    const float* b_bin  = (const float*)d_in[7];
    float* out = (float*)d_out;

    unsigned short* Hhi  = (unsigned short*)d_ws;
    float*          C    = (float*)((char*)d_ws + 33554432);
    unsigned short* Wext = (unsigned short*)((char*)d_ws + 67108864);

    static const int counts[11] = {512, 256, 128, 64, 32, 16, 8, 4, 2, 1, 1};
    static const int log2c[11]  = {9, 8, 7, 6, 5, 4, 3, 2, 1, 0, 0};
    int G[12]; G[0] = 0;
    for (int l = 0; l < 11; ++l) G[l + 1] = G[l] + 64 * counts[l];
    int off[11]; off[0] = 0;
    for (int l = 1; l < 11; ++l) off[l] = off[l - 1] + counts[l - 1];

    prep_w<<<640, 256, 0, stream>>>(W_bin, Wext);
    leaf_kernel<<<G[1] / 4, 256, 0, stream>>>(tokens, emb, Hhi, C, out, G[1]);

    for (int l = 1; l < 10; ++l) {
        int n = 64 * counts[l];
        int gm = (n + 127) / 128;
        bin3<<<dim3(gm, 4), 256, 0, stream>>>(Hhi, C, left, right, Wext, b_bin,
                                              out, G[l], n, off[l], log2c[l]);
    }

    un_kernel<<<4, 256, 0, stream>>>(Hhi, C, left, W_un, b_un, out, G[10], off[10]);
}